// Round 1
// baseline (250.507 us; speedup 1.0000x reference)
//
#include <hip/hip_runtime.h>
#include <math.h>

// Problem constants (match reference)
#define BB 8
#define DD 3
#define NN 4096
#define LATENT 256

#define CHUNK 256                      // points per block
#define NCHUNK (NN / CHUNK)            // 16
#define CHAMFER_BLOCKS (BB * 2 * NCHUNK)  // 256

// ---------------------------------------------------------------------------
// Chamfer kernel: each block handles 256 "query" points of one batch in one
// direction, stages the full opposite cloud in LDS as float4{y0,y1,y2,|y|^2},
// scans all 4096 candidates per thread, block-reduces sum of per-point
// min squared distances -> partial[blockIdx.x].
// dist(n,m) = |x_n|^2 + |y_m|^2 - 2 x_n.y_m ; min over m = sx + min(w_m - 2dot)
// ---------------------------------------------------------------------------
__global__ __launch_bounds__(256)
void chamfer_kernel(const float* __restrict__ recon,
                    const float* __restrict__ x,
                    float* __restrict__ partial)
{
    __shared__ float4 ly[NN];     // 64 KB
    __shared__ float red[4];

    const int blk = blockIdx.x;
    const int dir = blk >> 7;            // 0: query=recon, cloud=x ; 1: swapped
    const int rem = blk & 127;
    const int b   = rem >> 4;            // batch
    const int chk = rem & 15;            // chunk of 256 points
    const int tid = threadIdx.x;

    const float* cloud = (dir ? recon : x) + (size_t)b * DD * NN;
    const float* query = (dir ? x : recon) + (size_t)b * DD * NN;

    // Stage cloud into LDS (coalesced global reads, per-thread m index)
    for (int i = 0; i < NCHUNK; ++i) {
        int m = i * CHUNK + tid;
        float y0 = cloud[0 * NN + m];
        float y1 = cloud[1 * NN + m];
        float y2 = cloud[2 * NN + m];
        float w  = y0 * y0 + y1 * y1 + y2 * y2;
        ly[m] = make_float4(y0, y1, y2, w);
    }
    __syncthreads();

    // This thread's query point (registers)
    const int n = chk * CHUNK + tid;
    const float px = query[0 * NN + n];
    const float py = query[1 * NN + n];
    const float pz = query[2 * NN + n];
    const float sx = px * px + py * py + pz * pz;

    float mn = 3.4e38f;
#pragma unroll 8
    for (int m = 0; m < NN; ++m) {
        float4 q = ly[m];                         // broadcast ds_read_b128
        float dot = fmaf(px, q.x, fmaf(py, q.y, pz * q.z));
        mn = fminf(mn, fmaf(-2.0f, dot, q.w));
    }
    float val = sx + mn;                          // per-point min sq-dist

    // Block reduction (4 waves of 64)
    for (int off = 32; off > 0; off >>= 1)
        val += __shfl_down(val, off);
    if ((tid & 63) == 0) red[tid >> 6] = val;
    __syncthreads();
    if (tid == 0)
        partial[blk] = red[0] + red[1] + red[2] + red[3];
}

// ---------------------------------------------------------------------------
// Finalize: sum 256 chamfer partials, compute KL over 8x256, write 3 outputs.
// Fully deterministic (fixed reduction order per lane layout).
// ---------------------------------------------------------------------------
__global__ __launch_bounds__(256)
void finalize_kernel(const float* __restrict__ partial,
                     const float* __restrict__ mu,
                     const float* __restrict__ logvar,
                     float* __restrict__ out)
{
    __shared__ float redA[4];
    __shared__ float redB[4];
    const int tid = threadIdx.x;

    float s = partial[tid];   // exactly 256 partials

    float kl = 0.0f;
    for (int i = tid; i < BB * LATENT; i += 256) {
        float m  = mu[i];
        float lv = logvar[i];
        kl += 1.0f + lv - m * m - expf(lv);
    }

    for (int off = 32; off > 0; off >>= 1) {
        s  += __shfl_down(s, off);
        kl += __shfl_down(kl, off);
    }
    if ((tid & 63) == 0) { redA[tid >> 6] = s; redB[tid >> 6] = kl; }
    __syncthreads();
    if (tid == 0) {
        float chamfer_sum = redA[0] + redA[1] + redA[2] + redA[3];
        float kl_sum      = redB[0] + redB[1] + redB[2] + redB[3];
        // recon = mean(min_x) + mean(min_y); both means over B*N = 32768
        float recon = chamfer_sum / (float)(BB * NN);
        float kld   = -0.5f * kl_sum / (float)BB;
        out[0] = recon + kld;   // total (BETA = 1)
        out[1] = recon;
        out[2] = kld;
    }
}

extern "C" void kernel_launch(void* const* d_in, const int* in_sizes, int n_in,
                              void* d_out, int out_size, void* d_ws, size_t ws_size,
                              hipStream_t stream)
{
    const float* recon  = (const float*)d_in[0];
    const float* x      = (const float*)d_in[1];
    const float* mu     = (const float*)d_in[2];
    const float* logvar = (const float*)d_in[3];
    float* out = (float*)d_out;
    float* partial = (float*)d_ws;    // 256 floats

    chamfer_kernel<<<CHAMFER_BLOCKS, 256, 0, stream>>>(recon, x, partial);
    finalize_kernel<<<1, 256, 0, stream>>>(partial, mu, logvar, out);
}

// Round 2
// 35.310 us; speedup vs baseline: 7.0945x; 7.0945x over previous
//
#include <hip/hip_runtime.h>
#include <math.h>

// Problem constants (match reference)
#define BB 8
#define DD 3
#define NN 4096
#define LATENT 256

#define Q 8                         // queries per thread (ILP + LDS amortization)
#define THREADS 256
#define QB (Q * THREADS)            // 2048 queries per block
#define QTILES (NN / QB)            // 2
#define BLOCKS_X (2 * BB * QTILES)  // 32  (dir x batch x qtile)
#define TOTQ (2 * BB * NN)          // 65536 total (dir,b,n) query slots

// ---------------------------------------------------------------------------
// Stage 1: block (bx, c) = (dir,b,qtile) x candidate-tile c.
// Stages T = NN/C candidates into dynamic LDS as {-2y0,-2y1,-2y2,|y|^2};
// each thread scans the tile for its 8 query points (8 independent min
// chains). Per pair: 3 FMA + 1 min. Writes sx + tile-min to partial.
// ---------------------------------------------------------------------------
__global__ __launch_bounds__(THREADS)
void chamfer_stage1(const float* __restrict__ recon,
                    const float* __restrict__ x,
                    float* __restrict__ partial,
                    int C, int T)
{
    extern __shared__ float4 ly[];   // T * 16 bytes

    const int bx  = blockIdx.x;      // 0..31
    const int c   = blockIdx.y;      // 0..C-1
    const int dir = bx >> 4;
    const int rem = bx & 15;
    const int b   = rem >> 1;
    const int qt  = rem & 1;
    const int tid = threadIdx.x;

    const float* cloud = (dir ? recon : x) + (size_t)b * DD * NN;
    const float* query = (dir ? x : recon) + (size_t)b * DD * NN;

    // Stage this block's candidate tile (pre-scaled) into LDS
    for (int i = tid; i < T; i += THREADS) {
        int m = c * T + i;
        float y0 = cloud[0 * NN + m];
        float y1 = cloud[1 * NN + m];
        float y2 = cloud[2 * NN + m];
        ly[i] = make_float4(-2.0f * y0, -2.0f * y1, -2.0f * y2,
                            y0 * y0 + y1 * y1 + y2 * y2);
    }
    __syncthreads();

    float px[Q], py[Q], pz[Q], mn[Q];
    const int q0 = qt * QB + tid;
#pragma unroll
    for (int k = 0; k < Q; ++k) {
        int q = q0 + k * THREADS;
        px[k] = query[0 * NN + q];
        py[k] = query[1 * NN + q];
        pz[k] = query[2 * NN + q];
        mn[k] = 3.4e38f;
    }

#pragma unroll 4
    for (int m = 0; m < T; ++m) {
        float4 v = ly[m];            // broadcast ds_read_b128, serves 8 pairs
#pragma unroll
        for (int k = 0; k < Q; ++k) {
            float t = fmaf(px[k], v.x, fmaf(py[k], v.y, fmaf(pz[k], v.z, v.w)));
            mn[k] = fminf(mn[k], t);
        }
    }

    // partial[c][dir][b][n] : coalesced writes
    float* dst = partial + (size_t)c * TOTQ + (size_t)dir * (BB * NN) + b * NN + q0;
#pragma unroll
    for (int k = 0; k < Q; ++k) {
        float sx = px[k] * px[k] + py[k] * py[k] + pz[k] * pz[k];
        dst[k * THREADS] = sx + mn[k];
    }
}

// ---------------------------------------------------------------------------
// Stage 2: min across the C candidate tiles per query, then block-sum.
// 256 blocks x 256 threads, one query slot per thread.
// ---------------------------------------------------------------------------
__global__ __launch_bounds__(THREADS)
void chamfer_stage2(const float* __restrict__ partial,
                    float* __restrict__ sums, int C)
{
    __shared__ float red[4];
    const int tid = threadIdx.x;
    const int gq  = blockIdx.x * THREADS + tid;

    float m = partial[gq];
    for (int cc = 1; cc < C; ++cc)
        m = fminf(m, partial[(size_t)cc * TOTQ + gq]);

    for (int off = 32; off > 0; off >>= 1)
        m += __shfl_down(m, off);
    if ((tid & 63) == 0) red[tid >> 6] = m;
    __syncthreads();
    if (tid == 0)
        sums[blockIdx.x] = red[0] + red[1] + red[2] + red[3];
}

// ---------------------------------------------------------------------------
// Finalize: sum 256 block sums, compute KL over 8x256, write 3 outputs.
// ---------------------------------------------------------------------------
__global__ __launch_bounds__(THREADS)
void finalize_kernel(const float* __restrict__ sums,
                     const float* __restrict__ mu,
                     const float* __restrict__ logvar,
                     float* __restrict__ out)
{
    __shared__ float redA[4];
    __shared__ float redB[4];
    const int tid = threadIdx.x;

    float s = sums[tid];   // exactly 256 partial sums

    float kl = 0.0f;
    for (int i = tid; i < BB * LATENT; i += THREADS) {
        float m  = mu[i];
        float lv = logvar[i];
        kl += 1.0f + lv - m * m - expf(lv);
    }

    for (int off = 32; off > 0; off >>= 1) {
        s  += __shfl_down(s, off);
        kl += __shfl_down(kl, off);
    }
    if ((tid & 63) == 0) { redA[tid >> 6] = s; redB[tid >> 6] = kl; }
    __syncthreads();
    if (tid == 0) {
        float chamfer_sum = redA[0] + redA[1] + redA[2] + redA[3];
        float kl_sum      = redB[0] + redB[1] + redB[2] + redB[3];
        float recon = chamfer_sum / (float)(BB * NN);   // mean over both dirs
        float kld   = -0.5f * kl_sum / (float)BB;
        out[0] = recon + kld;
        out[1] = recon;
        out[2] = kld;
    }
}

extern "C" void kernel_launch(void* const* d_in, const int* in_sizes, int n_in,
                              void* d_out, int out_size, void* d_ws, size_t ws_size,
                              hipStream_t stream)
{
    const float* recon  = (const float*)d_in[0];
    const float* x      = (const float*)d_in[1];
    const float* mu     = (const float*)d_in[2];
    const float* logvar = (const float*)d_in[3];
    float* out = (float*)d_out;

    // Pick the largest candidate split C whose partial buffer fits d_ws.
    int C = 1;
    for (int c = 16; c >= 1; c >>= 1) {
        size_t need = (size_t)c * TOTQ * sizeof(float) + 256 * sizeof(float);
        if (need <= ws_size) { C = c; break; }
    }
    const int T = NN / C;

    float* partial = (float*)d_ws;                 // C * 65536 floats
    float* sums    = partial + (size_t)C * TOTQ;   // 256 floats

    dim3 g1(BLOCKS_X, C);
    size_t lds = (size_t)T * sizeof(float4);
    chamfer_stage1<<<g1, THREADS, lds, stream>>>(recon, x, partial, C, T);
    chamfer_stage2<<<256, THREADS, 0, stream>>>(partial, sums, C);
    finalize_kernel<<<1, THREADS, 0, stream>>>(sums, mu, logvar, out);
}